// Round 6
// baseline (295.045 us; speedup 1.0000x reference)
//
#include <hip/hip_runtime.h>
#include <cmath>

#define BB 4
#define NN 4096
#define DD 244
#define DP 256
#define FSP 96
#define KC 3       // FSP/32 k-chunks for scores
#define NCH 4      // m-chunks per row in pv_flash
#define TPCH 32    // m-tiles per chunk (uniform)
#define WV 4       // waves per pv block

typedef _Float16 half8 __attribute__((ext_vector_type(8)));
typedef float float4v __attribute__((ext_vector_type(4)));
typedef unsigned int uint;

#define MFMA16 __builtin_amdgcn_mfma_f32_16x16x32_f16

static __device__ __forceinline__ uint pack2(float a, float b) {
    _Float16 ha = (_Float16)a, hb = (_Float16)b;
    unsigned short ua = __builtin_bit_cast(unsigned short, ha);
    unsigned short ub = __builtin_bit_cast(unsigned short, hb);
    return (uint)ua | ((uint)ub << 16);
}

// ---------------- prep kernels ----------------
__global__ __launch_bounds__(256) void prep_w(const float* __restrict__ Wv,
                                              const float* __restrict__ Wo,
                                              _Float16* __restrict__ Wvh,
                                              _Float16* __restrict__ Woh) {
    int r = blockIdx.x, k = threadIdx.x;
    const float* src = blockIdx.y ? Wo : Wv;
    _Float16* dst = blockIdx.y ? Woh : Wvh;
    dst[(size_t)r * DP + k] =
        (r < DD && k < DD) ? (_Float16)src[(size_t)r * DD + k] : (_Float16)0.f;
}

// feature order: k 0..63 = shell, 64 = charge, 65 = sqrt(mass), 66..95 = 0
// Qb = -weight * feat  (so score = dot(Qb_n, Kb_m) - 0.3|n-m| = -energy)
__global__ __launch_bounds__(64) void prep_feat(const float* __restrict__ charge,
                                                const float* __restrict__ shell,
                                                const float* __restrict__ mass,
                                                _Float16* __restrict__ Qb,
                                                _Float16* __restrict__ Kb) {
    size_t row = blockIdx.x; int t = threadIdx.x;
    float v = shell[row * 64 + t];
    Kb[row * FSP + t] = (_Float16)v;
    Qb[row * FSP + t] = (_Float16)(-0.5f * v);
    int k2 = 64 + t;
    if (k2 < FSP) {
        float v2 = 0.f, q2 = 0.f;
        if (t == 0) { v2 = charge[row]; q2 = -1.0f * v2; }
        else if (t == 1) { v2 = sqrtf(mass[row]); q2 = -0.1f * v2; }
        Kb[row * FSP + k2] = (_Float16)v2;
        Qb[row * FSP + k2] = (_Float16)q2;
    }
}

// Vh [B*N][DP] f16 -> Vt [B][DP][N] f16
__global__ __launch_bounds__(256) void transpose_v(const _Float16* __restrict__ Vh,
                                                   _Float16* __restrict__ Vt) {
    __shared__ _Float16 tile[64][65];
    int n0 = blockIdx.x * 64, d0 = blockIdx.y * 64, b = blockIdx.z;
    int t = threadIdx.x;
#pragma unroll
    for (int i = 0; i < 16; ++i) {
        int idx = t + 256 * i;
        int r = idx >> 6, cc = idx & 63;
        tile[r][cc] = Vh[(size_t)(b * NN + n0 + r) * DP + d0 + cc];
    }
    __syncthreads();
#pragma unroll
    for (int i = 0; i < 16; ++i) {
        int idx = t + 256 * i;
        int dr = idx >> 6, nc = idx & 63;
        Vt[(size_t)b * DP * NN + (size_t)(d0 + dr) * NN + n0 + nc] = tile[nc][dr];
    }
}

// ---------------- 4-wave MFMA GEMM: C[r][c] = sum_k A[r][k]*W[c][k] + bias[c]
// block tile 64 rows x 128 cols; wave tile 32x64 (acc[2][4]); K = 256 (8 steps)
template <bool AF32, bool F16OUT>
__global__ __launch_bounds__(256) void gemm2(const void* __restrict__ A_,
                                             const _Float16* __restrict__ W,
                                             const float* __restrict__ bias,
                                             void* __restrict__ Cout) {
    int t = threadIdx.x;
    int w = t >> 6, l = t & 63, c = l & 15, g = l >> 4;
    int wr = w >> 1, wc = w & 1;
    int rowbase = blockIdx.x * 64 + wr * 32;
    int colbase = blockIdx.y * 128 + wc * 64;
    float4v acc[2][4];
#pragma unroll
    for (int i = 0; i < 2; ++i)
#pragma unroll
        for (int j = 0; j < 4; ++j) acc[i][j] = (float4v){0.f, 0.f, 0.f, 0.f};
#pragma unroll
    for (int kc = 0; kc < 8; ++kc) {
        int k0 = kc * 32 + g * 8;
        half8 af[2];
#pragma unroll
        for (int i = 0; i < 2; ++i) {
            int row = rowbase + 16 * i + c;
            if constexpr (AF32) {
                const float* ap = (const float*)A_ + (size_t)row * DD;
                float4 a0 = (k0 < DD) ? *(const float4*)(ap + k0) : make_float4(0, 0, 0, 0);
                float4 a1 = (k0 + 4 < DD) ? *(const float4*)(ap + k0 + 4) : make_float4(0, 0, 0, 0);
                af[i] = (half8){(_Float16)a0.x, (_Float16)a0.y, (_Float16)a0.z, (_Float16)a0.w,
                                (_Float16)a1.x, (_Float16)a1.y, (_Float16)a1.z, (_Float16)a1.w};
            } else {
                af[i] = *(const half8*)((const _Float16*)A_ + (size_t)row * DP + k0);
            }
        }
        half8 bf[4];
#pragma unroll
        for (int j = 0; j < 4; ++j)
            bf[j] = *(const half8*)(W + (size_t)(colbase + 16 * j + c) * DP + k0);
#pragma unroll
        for (int i = 0; i < 2; ++i)
#pragma unroll
            for (int j = 0; j < 4; ++j)
                acc[i][j] = MFMA16(af[i], bf[j], acc[i][j], 0, 0, 0);
    }
#pragma unroll
    for (int i = 0; i < 2; ++i)
#pragma unroll
        for (int j = 0; j < 4; ++j) {
            int col = colbase + 16 * j + c;
            float bcol = (col < DD) ? bias[col] : 0.f;
#pragma unroll
            for (int r = 0; r < 4; ++r) {
                int row = rowbase + 16 * i + 4 * g + r;
                float v = acc[i][j][r] + bcol;
                if constexpr (F16OUT) {
                    ((_Float16*)Cout)[(size_t)row * DP + col] = (_Float16)v;
                } else {
                    if (col < DD) ((float*)Cout)[(size_t)row * DD + col] = v;
                }
            }
        }
}

// ---------------- fused flash PV+stats over one uniform m-chunk ----------------
// block (bx, ch): rows n0..n0+31, m-tiles [ch*32, ch*32+32) — ALL tiles (stats
// need full range); V-contraction only for causal tiles. Writes per-chunk
// partials: partS (M, F, S) and partO (unscaled acc, only if chunk has causal m).
__global__ __launch_bounds__(256, 4) void pv_flash(const _Float16* __restrict__ Qb,
                                                   const _Float16* __restrict__ Kb,
                                                   const _Float16* __restrict__ Vt,
                                                   float* __restrict__ partS,
                                                   float* __restrict__ partO) {
    __shared__ __align__(16) uint Plds[WV][2][16][20];  // masked P, f16-packed
    __shared__ float SmLds[WV][2][16][2];               // tile-max share / F,S merge
    int t = threadIdx.x;
    int w = t >> 6, l = t & 63, c = l & 15, g = l >> 4;
    int gx = blockIdx.x, b = blockIdx.y;
    int bx = gx & 127, ch = gx >> 7;
    size_t bN = (size_t)b * NN;
    int n0 = bx * 32;
    int t0 = ch * TPCH;
    half8 qf[2][KC];
#pragma unroll
    for (int qg = 0; qg < 2; ++qg)
#pragma unroll
        for (int kc = 0; kc < KC; ++kc)
            qf[qg][kc] = *(const half8*)(Qb + (bN + n0 + 16 * qg + c) * FSP + kc * 32 + g * 8);
    int nq[2] = {n0 + c, n0 + 16 + c};
    float M[2] = {-1e30f, -1e30f}, F[2] = {0.f, 0.f}, S[2] = {0.f, 0.f};
    float4v acc[2][4];
#pragma unroll
    for (int qg = 0; qg < 2; ++qg)
#pragma unroll
        for (int d = 0; d < 4; ++d) acc[qg][d] = (float4v){0.f, 0.f, 0.f, 0.f};
    const _Float16* VtB = Vt + (size_t)b * DP * NN;

    for (int ro = 0; ro < TPCH / WV; ++ro) {
        int tt = t0 + ro * WV + w;
        int m0 = tt * 32;
        // ---- ph1: scores for my tile (kept in regs) + per-row tile max ----
        float sv[2][8];
        {
            half8 kf[2][KC];
#pragma unroll
            for (int s = 0; s < 2; ++s)
#pragma unroll
                for (int kc = 0; kc < KC; ++kc)
                    kf[s][kc] = *(const half8*)(Kb + (bN + m0 + 16 * s + c) * FSP + kc * 32 + g * 8);
#pragma unroll
            for (int qg = 0; qg < 2; ++qg)
#pragma unroll
                for (int s = 0; s < 2; ++s) {
                    float4v p = (float4v){0.f, 0.f, 0.f, 0.f};
#pragma unroll
                    for (int kc = 0; kc < KC; ++kc) p = MFMA16(kf[s][kc], qf[qg][kc], p, 0, 0, 0);
#pragma unroll
                    for (int r = 0; r < 4; ++r) {
                        int m = m0 + 16 * s + 4 * g + r;
                        sv[qg][4 * s + r] = p[r] - 0.3f * fabsf((float)(nq[qg] - m));
                    }
                }
        }
        float tm[2];
#pragma unroll
        for (int qg = 0; qg < 2; ++qg) {
            float x0 = sv[qg][0];
#pragma unroll
            for (int i = 1; i < 8; ++i) x0 = fmaxf(x0, sv[qg][i]);
            x0 = fmaxf(x0, __shfl_xor(x0, 16));
            x0 = fmaxf(x0, __shfl_xor(x0, 32));
            tm[qg] = x0;
        }
        if (g == 0) { SmLds[w][0][c][0] = tm[0]; SmLds[w][1][c][0] = tm[1]; }
        __syncthreads();
        // ---- ph2: shared new max, rescale running stats+acc, write masked P ----
        float corr[2];
#pragma unroll
        for (int qg = 0; qg < 2; ++qg) {
            float tmax = SmLds[0][qg][c][0];
#pragma unroll
            for (int ww = 1; ww < WV; ++ww) tmax = fmaxf(tmax, SmLds[ww][qg][c][0]);
            float Mn = fmaxf(M[qg], tmax);
            corr[qg] = __expf(M[qg] - Mn);
            F[qg] *= corr[qg]; S[qg] *= corr[qg];
            M[qg] = Mn;
        }
        if (!(__all(corr[0] == 1.0f) && __all(corr[1] == 1.0f))) {
#pragma unroll
            for (int qg = 0; qg < 2; ++qg)
#pragma unroll
                for (int r = 0; r < 4; ++r) {
                    float a = __shfl(corr[qg], 4 * g + r);
#pragma unroll
                    for (int d = 0; d < 4; ++d) acc[qg][d][r] *= a;
                }
        }
#pragma unroll
        for (int qg = 0; qg < 2; ++qg) {
#pragma unroll
            for (int s = 0; s < 2; ++s) {
                float wv4[4];
#pragma unroll
                for (int r = 0; r < 4; ++r) {
                    int m = m0 + 16 * s + 4 * g + r;
                    float e = __expf(sv[qg][4 * s + r] - M[qg]);
                    F[qg] += e;
                    float wm = (m <= nq[qg]) ? e : 0.f;
                    S[qg] += wm;
                    wv4[r] = wm;
                }
                uint* dst = &Plds[w][qg][c][8 * s + 2 * g];
                dst[0] = pack2(wv4[0], wv4[1]);
                dst[1] = pack2(wv4[2], wv4[3]);
            }
        }
        __syncthreads();
        // ---- ph3: causal V-contraction (my dc-quarter, all 4 P-tiles) ----
        if (t0 + ro * WV <= bx) {
#pragma unroll
            for (int ww = 0; ww < WV; ++ww) {
                if (t0 + ro * WV + ww <= bx) {
                    int m0p = (t0 + ro * WV + ww) * 32;
                    half8 pa0 = *(const half8*)&Plds[ww][0][c][4 * g];
                    half8 pa1 = *(const half8*)&Plds[ww][1][c][4 * g];
#pragma unroll
                    for (int dcl = 0; dcl < 4; ++dcl) {
                        int dc = 4 * w + dcl;
                        half8 vf = *(const half8*)(VtB + (size_t)(dc * 16 + c) * NN + m0p + g * 8);
                        acc[0][dcl] = MFMA16(pa0, vf, acc[0][dcl], 0, 0, 0);
                        acc[1][dcl] = MFMA16(pa1, vf, acc[1][dcl], 0, 0, 0);
                    }
                }
            }
        }
    }
    // ---- tail: merge F,S over g-groups (M already row-consistent), then waves ----
#pragma unroll
    for (int qg = 0; qg < 2; ++qg) {
        F[qg] += __shfl_xor(F[qg], 16); F[qg] += __shfl_xor(F[qg], 32);
        S[qg] += __shfl_xor(S[qg], 16); S[qg] += __shfl_xor(S[qg], 32);
    }
    if (g == 0) {
        SmLds[w][0][c][0] = F[0]; SmLds[w][0][c][1] = S[0];
        SmLds[w][1][c][0] = F[1]; SmLds[w][1][c][1] = S[1];
    }
    __syncthreads();
    if (t < 32) {
        int qg = t >> 4, cc = t & 15;
        float Ft = 0.f, St = 0.f;
#pragma unroll
        for (int ww = 0; ww < WV; ++ww) { Ft += SmLds[ww][qg][cc][0]; St += SmLds[ww][qg][cc][1]; }
        size_t bn = bN + n0 + 16 * qg + cc;
        size_t idx = ((size_t)ch * (BB * NN) + bn) * 3;
        partS[idx + 0] = M[qg];
        partS[idx + 1] = Ft;
        partS[idx + 2] = St;
    }
    if (t0 <= bx) {
#pragma unroll
        for (int qg = 0; qg < 2; ++qg)
#pragma unroll
            for (int r = 0; r < 4; ++r) {
                int nn = n0 + 16 * qg + 4 * g + r;
                size_t base = ((size_t)ch * (BB * NN) + bN + nn) * DP;
#pragma unroll
                for (int dcl = 0; dcl < 4; ++dcl)
                    partO[base + (4 * w + dcl) * 16 + c] = acc[qg][dcl][r];
            }
    }
}

// ---------------- finalize: merge chunk partials -> alpha -> Oh ----------------
__global__ __launch_bounds__(256) void finalize(const float* __restrict__ partS,
                                                const float* __restrict__ partO,
                                                const float* __restrict__ valence,
                                                _Float16* __restrict__ Oh) {
    int n = blockIdx.x, b = blockIdx.y;
    size_t bn = (size_t)b * NN + n;
    int d = threadIdx.x;
    float Ms[NCH], Fs[NCH], Ss[NCH];
    float M = -1e30f;
#pragma unroll
    for (int ch = 0; ch < NCH; ++ch) {
        size_t idx = ((size_t)ch * (BB * NN) + bn) * 3;
        Ms[ch] = partS[idx + 0]; Fs[ch] = partS[idx + 1]; Ss[ch] = partS[idx + 2];
        M = fmaxf(M, Ms[ch]);
    }
    float F = 0.f, S = 0.f;
#pragma unroll
    for (int ch = 0; ch < NCH; ++ch) {
        float wc = __expf(Ms[ch] - M);
        F += Fs[ch] * wc; S += Ss[ch] * wc;
    }
    float val = valence[bn];
    float scale = fminf(val / (1.0f + 1e-6f), 1.0f);
    float alpha = scale / (scale * S + 1e-8f * F);
    int nch = (n >> 10) + 1;  // chunks containing causal m for this row
    float o = 0.f;
    for (int ch = 0; ch < nch; ++ch)
        o += __expf(Ms[ch] - M) * partO[((size_t)ch * (BB * NN) + bn) * DP + d];
    Oh[bn * DP + d] = (_Float16)(alpha * o);
}

// ---------------- launch ----------------
extern "C" void kernel_launch(void* const* d_in, const int* in_sizes, int n_in,
                              void* d_out, int out_size, void* d_ws, size_t ws_size,
                              hipStream_t stream) {
    (void)in_sizes; (void)n_in; (void)out_size; (void)ws_size;
    const float* charge  = (const float*)d_in[0];
    const float* shell   = (const float*)d_in[1];
    const float* mass    = (const float*)d_in[2];
    const float* valence = (const float*)d_in[3];
    const float* x  = (const float*)d_in[5];
    const float* Wv = (const float*)d_in[6];
    const float* bv = (const float*)d_in[7];
    const float* Wo = (const float*)d_in[8];
    const float* bo = (const float*)d_in[9];
    float* out = (float*)d_out;

    const size_t BN = (size_t)BB * NN;
    char* w = (char*)d_ws;
    _Float16* Qb  = (_Float16*)w;              w += BN * FSP * 2;            // 3.1 MB
    _Float16* Kb  = (_Float16*)w;              w += BN * FSP * 2;            // 3.1 MB
    _Float16* Vh  = (_Float16*)w;              w += BN * DP * 2;             // 8.4 MB (reused as Oh)
    _Float16* Vt  = (_Float16*)w;              w += BN * DP * 2;             // 8.4 MB
    _Float16* Wvh = (_Float16*)w;              w += DP * DP * 2;
    _Float16* Woh = (_Float16*)w;              w += DP * DP * 2;
    float* partS  = (float*)w;                 w += (size_t)NCH * BN * 3 * 4; // 0.8 MB
    float* partO  = (float*)w;                 w += (size_t)NCH * BN * DP * 4;// 67 MB
    _Float16* Oh = Vh;  // Vh dead after transpose_v

    prep_w<<<dim3(DP, 2), 256, 0, stream>>>(Wv, Wo, Wvh, Woh);
    prep_feat<<<BB * NN, 64, 0, stream>>>(charge, shell, mass, Qb, Kb);
    gemm2<true, true><<<dim3(BB * NN / 64, DP / 128), 256, 0, stream>>>(x, Wvh, bv, (void*)Vh);
    transpose_v<<<dim3(NN / 64, DP / 64, BB), 256, 0, stream>>>(Vh, Vt);
    pv_flash<<<dim3((NN / 32) * NCH, BB), 256, 0, stream>>>(Qb, Kb, Vt, partS, partO);
    finalize<<<dim3(NN, BB), 256, 0, stream>>>(partS, partO, valence, Oh);
    gemm2<false, false><<<dim3(BB * NN / 64, DP / 128), 256, 0, stream>>>(Oh, Woh, bo, (void*)out);
}